// Round 7
// baseline (105.905 us; speedup 1.0000x reference)
//
#include <hip/hip_runtime.h>
#include <hip/hip_bf16.h>
#include <cstddef>
#include <cstdint>

#define B_      2
#define QD_     128
#define NQ_     (QD_ * QD_)          // 16384
#define EMBED_  256
#define HEADS_  8
#define POINTS_ 4
#define FFN_    512
#define RTOT_   (B_ * NQ_)           // 32768
#define NCATP_  384                  // 352 real cols padded to 384

using bf16x8 = __attribute__((ext_vector_type(8))) short;   // 8 bf16 = 4 VGPRs
using f32x4  = __attribute__((ext_vector_type(4))) float;   // MFMA accumulator

__device__ __forceinline__ short f2bf(float f) {
    unsigned u = __float_as_uint(f);
    u += 0x7FFFu + ((u >> 16) & 1u);          // round-to-nearest-even
    return (short)(u >> 16);
}
__device__ __forceinline__ float bf2f(short s) {
    return __uint_as_float(((unsigned)(unsigned short)s) << 16);
}

#define GLDS(gp, lp) __builtin_amdgcn_global_load_lds( \
        (const __attribute__((address_space(1))) void*)(gp), \
        (__attribute__((address_space(3))) void*)(lp), 16, 0, 0)

#define WCAT_ELEMS  (NCATP_ * 256)
#define WOUT_ELEMS  (256 * 256)
#define W1_ELEMS    (512 * 256)
#define W2_ELEMS    (256 * 512)
#define PREP_TOTAL  (WCAT_ELEMS + WOUT_ELEMS + W1_ELEMS + W2_ELEMS)   // 425984
#define CVT_BLOCKS  (RTOT_ * EMBED_ / 8 / 256)                         // 4096
#define PREP_BLOCKS ((PREP_TOTAL + 255) / 256)                         // 1664

// ---------------------------------------------------------------------------
// Fused prep: q->bf16 (blocks [0,4096)) + weight transpose/concat (rest).
// ---------------------------------------------------------------------------
__global__ __launch_bounds__(256) void prep_all(
        const float* __restrict__ q, short* __restrict__ qbf,
        const float* __restrict__ Wv, const float* __restrict__ Wo,
        const float* __restrict__ Wa, const float* __restrict__ bv,
        const float* __restrict__ bo, const float* __restrict__ ba,
        const float* __restrict__ W_out, const float* __restrict__ W1,
        const float* __restrict__ W2,
        short* __restrict__ WcatT, short* __restrict__ WoutT,
        short* __restrict__ W1T, short* __restrict__ W2T,
        float* __restrict__ bcat) {
    const int b = blockIdx.x;
    if (b < CVT_BLOCKS) {
        const size_t i = (size_t)b * 256 + threadIdx.x;
        const float4 f0 = *(const float4*)(q + i * 8);
        const float4 f1 = *(const float4*)(q + i * 8 + 4);
        bf16x8 v;
        v[0] = f2bf(f0.x); v[1] = f2bf(f0.y); v[2] = f2bf(f0.z); v[3] = f2bf(f0.w);
        v[4] = f2bf(f1.x); v[5] = f2bf(f1.y); v[6] = f2bf(f1.z); v[7] = f2bf(f1.w);
        *(bf16x8*)(qbf + i * 8) = v;
        return;
    }
    int idx = (b - CVT_BLOCKS) * 256 + threadIdx.x;
    if (idx < WCAT_ELEMS) {
        int c = idx >> 8, k = idx & 255;
        float v = 0.f;
        if (c < 256)      v = Wv[k * 256 + c];
        else if (c < 320) v = Wo[k * 64 + (c - 256)];
        else if (c < 352) v = Wa[k * 32 + (c - 320)];
        WcatT[idx] = f2bf(v);
    } else if (idx < WCAT_ELEMS + WOUT_ELEMS) {
        int j = idx - WCAT_ELEMS; int c = j >> 8, k = j & 255;
        WoutT[j] = f2bf(W_out[k * 256 + c]);
    } else if (idx < WCAT_ELEMS + WOUT_ELEMS + W1_ELEMS) {
        int j = idx - (WCAT_ELEMS + WOUT_ELEMS); int c = j >> 8, k = j & 255;
        W1T[j] = f2bf(W1[k * 512 + c]);
    } else if (idx < PREP_TOTAL) {
        int j = idx - (WCAT_ELEMS + WOUT_ELEMS + W1_ELEMS); int c = j >> 9, k = j & 511;
        W2T[j] = f2bf(W2[k * 256 + c]);
    }
    if (idx < NCATP_) {
        float v = 0.f;
        if (idx < 256)      v = bv[idx];
        else if (idx < 320) v = bo[idx - 256];
        else if (idx < 352) v = ba[idx - 320];
        bcat[idx] = v;
    }
}

// ---------------------------------------------------------------------------
// bf16 MFMA GEMM, 2-phase double-buffered.
// BM=BN=128, BK=64, 4 waves (2x2), 64x64/wave, 16x16x32 MFMA.
// ---------------------------------------------------------------------------
enum { EP_RELU_BF16 = 1, EP_ADD2Q_BF16 = 2, EP_SPLIT = 3 };

template <int EP>
__global__ __launch_bounds__(256) void gemm_mfma(
        const short* __restrict__ A,            // [M][K] bf16
        const short* __restrict__ Bt,           // [N][K] bf16
        const float* __restrict__ bias,         // [N]
        const short* __restrict__ extra,        // qbf (ADD2Q) else nullptr
        float* __restrict__ Cf,                 // pm (SPLIT) else nullptr
        short* __restrict__ Cb,                 // bf16 out
        int M, int N, int K) {
    __shared__ __align__(16) short As[2][128 * 64];
    __shared__ __align__(16) short Bs[2][128 * 64];

    const int t    = threadIdx.x;
    const int ln   = t & 63;
    const int w    = t >> 6;
    const int wr   = w >> 1;
    const int wc   = w & 1;
    const int lrow = ln & 15;
    const int lkg  = ln >> 4;

    const int gx   = gridDim.x;
    const int nwg  = gx * gridDim.y;
    const int flat = blockIdx.y * gx + blockIdx.x;
    const int q8   = nwg >> 3;
    const int swz  = (flat & 7) * q8 + (flat >> 3);
    const int row0 = (swz / gx) * 128;
    const int col0 = (swz % gx) * 128;

    f32x4 acc[4][4] = {};

    auto stage = [&](int buf, int k0) {
        #pragma unroll
        for (int j = 0; j < 4; ++j) {
            const int c0 = (w * 4 + j) * 64;
            const int c  = c0 + ln;
            const int r  = c >> 3;
            const int s  = (c & 7) ^ (r & 7);
            GLDS(A  + (size_t)(row0 + r) * K + (k0 + s * 8), &As[buf][c0 * 8]);
            GLDS(Bt + (size_t)(col0 + r) * K + (k0 + s * 8), &Bs[buf][c0 * 8]);
        }
    };

    stage(0, 0);
    __syncthreads();
    int cur = 0;
    for (int k0 = 0; k0 < K; k0 += 64) {
        if (k0 + 64 < K) stage(cur ^ 1, k0 + 64);
        #pragma unroll
        for (int ks = 0; ks < 2; ++ks) {
            const int slot = ((ks * 4 + lkg) ^ (lrow & 7)) * 8;
            bf16x8 af[4], bfr[4];
            #pragma unroll
            for (int m = 0; m < 4; ++m)
                af[m] = *(const bf16x8*)&As[cur][(wr * 64 + m * 16 + lrow) * 64 + slot];
            #pragma unroll
            for (int n = 0; n < 4; ++n)
                bfr[n] = *(const bf16x8*)&Bs[cur][(wc * 64 + n * 16 + lrow) * 64 + slot];
            #pragma unroll
            for (int m = 0; m < 4; ++m)
                #pragma unroll
                for (int n = 0; n < 4; ++n)
                    acc[m][n] = __builtin_amdgcn_mfma_f32_16x16x32_bf16(
                        af[m], bfr[n], acc[m][n], 0, 0, 0);
        }
        __syncthreads();
        cur ^= 1;
    }

    const int orow = (ln >> 4) * 4;
    const int ocol = ln & 15;
    #pragma unroll
    for (int m = 0; m < 4; ++m) {
        #pragma unroll
        for (int n = 0; n < 4; ++n) {
            const int col = col0 + wc * 64 + n * 16 + ocol;
            const float bv = bias[col];
            #pragma unroll
            for (int rr = 0; rr < 4; ++rr) {
                const int row = row0 + wr * 64 + m * 16 + orow + rr;
                float v = acc[m][n][rr] + bv;
                if (EP == EP_SPLIT) {
                    if (col < 256) Cb[(size_t)row * 256 + col] = f2bf(v);
                    else           Cf[(size_t)row * 128 + (col - 256)] = v;
                } else if (EP == EP_RELU_BF16) {
                    Cb[(size_t)row * N + col] = f2bf(fmaxf(v, 0.f));
                } else if (EP == EP_ADD2Q_BF16) {
                    v += 2.f * bf2f(extra[(size_t)row * N + col]);
                    Cb[(size_t)row * N + col] = f2bf(v);
                }
            }
        }
    }
}

// ---------------------------------------------------------------------------
// Fused W2 GEMM + LayerNorm + residual: out = x + LN(hid@W2 + b2)*g + beta
// BM=64 rows, BN=256 (full row), BK=64, 256 threads = 4 waves side-by-side
// (each wave 64 rows x 64 cols, acc[4][4]).
// LDS: As dbuf 2x8KB + Bs single 32KB (restaged from L2 per kt) + red 2KB
//  = 50 KB -> 3 resident blocks/CU; grid 512 -> 2/CU for cross-block overlap.
// ---------------------------------------------------------------------------
__global__ __launch_bounds__(256) void gemm_ln(
        const short* __restrict__ A,            // hid [M][512] bf16
        const short* __restrict__ Bt,           // W2T [256][512] bf16
        const float* __restrict__ bias,         // b2
        const short* __restrict__ xres,         // xbf [M][256] bf16
        const float* __restrict__ gamma, const float* __restrict__ beta,
        float* __restrict__ out, int M, int K) {
    __shared__ __align__(16) short As[2][64 * 64];    // 8 KB x2
    __shared__ __align__(16) short Bs[256 * 64];      // 32 KB
    __shared__ float red[64][4][2];                   // 2 KB

    const int t    = threadIdx.x;
    const int ln   = t & 63;
    const int w    = t >> 6;            // 0..3 col group (64 cols each)
    const int lrow = ln & 15;
    const int lkg  = ln >> 4;
    const int row0 = blockIdx.x * 64;

    f32x4 acc[4][4] = {};

    auto stage_a = [&](int buf, int k0) {
        #pragma unroll
        for (int j = 0; j < 2; ++j) {               // 512 chunks / 256 thr
            const int c0 = (w * 2 + j) * 64;
            const int c  = c0 + ln;
            const int r  = c >> 3;
            const int s  = (c & 7) ^ (r & 7);
            GLDS(A + (size_t)(row0 + r) * K + (k0 + s * 8), &As[buf][c0 * 8]);
        }
    };
    auto stage_b = [&](int k0) {
        #pragma unroll
        for (int j = 0; j < 8; ++j) {               // 2048 chunks / 256 thr
            const int c0 = (w * 8 + j) * 64;
            const int c  = c0 + ln;
            const int r  = c >> 3;
            const int s  = (c & 7) ^ (r & 7);
            GLDS(Bt + (size_t)r * K + (k0 + s * 8), &Bs[c0 * 8]);
        }
    };

    stage_a(0, 0);
    stage_b(0);
    __syncthreads();
    int buf = 0;
    for (int kt = 0; kt < 8; ++kt) {
        if (kt < 7) stage_a(buf ^ 1, kt * 64 + 64);     // runs under compute
        #pragma unroll
        for (int ks = 0; ks < 2; ++ks) {
            const int slot = ((ks * 4 + lkg) ^ (lrow & 7)) * 8;
            bf16x8 af[4], bfr[4];
            #pragma unroll
            for (int m = 0; m < 4; ++m)
                af[m] = *(const bf16x8*)&As[buf][(m * 16 + lrow) * 64 + slot];
            #pragma unroll
            for (int n = 0; n < 4; ++n)
                bfr[n] = *(const bf16x8*)&Bs[(w * 64 + n * 16 + lrow) * 64 + slot];
            #pragma unroll
            for (int m = 0; m < 4; ++m)
                #pragma unroll
                for (int n = 0; n < 4; ++n)
                    acc[m][n] = __builtin_amdgcn_mfma_f32_16x16x32_bf16(
                        af[m], bfr[n], acc[m][n], 0, 0, 0);
        }
        __syncthreads();                 // everyone done with Bs(kt)
        if (kt < 7) {
            stage_b(kt * 64 + 64);       // L2-resident W2 slice
            __syncthreads();             // Bs(kt+1) landed
        }
        buf ^= 1;
    }

    const int orow = lkg * 4;
    const int ocol = lrow;

    // bias into acc
    #pragma unroll
    for (int n = 0; n < 4; ++n) {
        const float bv = bias[w * 64 + n * 16 + ocol];
        #pragma unroll
        for (int m = 0; m < 4; ++m)
            #pragma unroll
            for (int rr = 0; rr < 4; ++rr)
                acc[m][n][rr] += bv;
    }

    // per-row partials over this wave's 64 cols (16-lane shuffle reduce)
    #pragma unroll
    for (int m = 0; m < 4; ++m) {
        #pragma unroll
        for (int rr = 0; rr < 4; ++rr) {
            float s = 0.f, sq = 0.f;
            #pragma unroll
            for (int n = 0; n < 4; ++n) {
                const float v = acc[m][n][rr];
                s += v; sq += v * v;
            }
            #pragma unroll
            for (int o = 1; o < 16; o <<= 1) {
                s  += __shfl_xor(s, o, 64);
                sq += __shfl_xor(sq, o, 64);
            }
            if (ocol == 0) {
                const int row = m * 16 + orow + rr;
                red[row][w][0] = s;
                red[row][w][1] = sq;
            }
        }
    }
    __syncthreads();

    // finalize LN + residual from xbf, write f32 out
    #pragma unroll
    for (int m = 0; m < 4; ++m) {
        #pragma unroll
        for (int rr = 0; rr < 4; ++rr) {
            const int row = m * 16 + orow + rr;
            const float S  = red[row][0][0] + red[row][1][0] + red[row][2][0] + red[row][3][0];
            const float SQ = red[row][0][1] + red[row][1][1] + red[row][2][1] + red[row][3][1];
            const float mean = S * (1.0f / 256.0f);
            const float var  = SQ * (1.0f / 256.0f) - mean * mean;
            const float rs   = rsqrtf(var + 1e-5f);
            const size_t rbase = (size_t)(row0 + row) * 256;
            #pragma unroll
            for (int n = 0; n < 4; ++n) {
                const int col = w * 64 + n * 16 + ocol;
                out[rbase + col] = bf2f(xres[rbase + col])
                                 + (acc[m][n][rr] - mean) * rs * gamma[col] + beta[col];
            }
        }
    }
}

// ---------------------------------------------------------------------------
// MSDA sampler, two-phase (unchanged).
// ---------------------------------------------------------------------------
__global__ __launch_bounds__(256) void msda_sample(
        const float* __restrict__ pm, const short* __restrict__ vcomp,
        short* __restrict__ msda) {
    __shared__ int   s_off[8][32][4];
    __shared__ float s_c[8][32][4];

    const int t  = threadIdx.x;
    const int r0 = blockIdx.x * 8;
    const int bq = r0 >> 14;

    {
        const int g = t >> 5, cmb = t & 31, h = cmb >> 2, p = cmb & 3;
        const int r = r0 + g;
        const int n = r & (NQ_ - 1);
        const int gi = n >> 7, gj = n & 127;
        const float* pr = pm + (size_t)r * 128;

        const float l0 = pr[64 + h * 4 + 0], l1 = pr[64 + h * 4 + 1];
        const float l2 = pr[64 + h * 4 + 2], l3 = pr[64 + h * 4 + 3];
        const float mx = fmaxf(fmaxf(l0, l1), fmaxf(l2, l3));
        const float sum = expf(l0 - mx) + expf(l1 - mx) + expf(l2 - mx) + expf(l3 - mx);
        const float lp = pr[64 + h * 4 + p];
        const float aw = expf(lp - mx) / sum;

        const float ox = pr[h * 8 + p * 2 + 0];
        const float oy = pr[h * 8 + p * 2 + 1];
        const float px = (gj * (1.0f / 127.0f) + ox * (1.0f / 128.0f)) * 128.0f - 0.5f;
        const float py = (gi * (1.0f / 127.0f) + oy * (1.0f / 128.0f)) * 128.0f - 0.5f;
        const float x0f = floorf(px), y0f = floorf(py);
        const int   x0 = (int)x0f, y0 = (int)y0f;
        const float fx = px - x0f, fy = py - y0f;
        const int x0c = min(max(x0, 0), 127), x1c = min(max(x0 + 1, 0), 127);
        const int y0c = min(max(y0, 0), 127), y1c = min(max(y0 + 1, 0), 127);
        const float vx0 = ((unsigned)x0 <= 127u) ? 1.f : 0.f;
        const float vx1 = ((unsigned)(x0 + 1) <= 127u) ? 1.f : 0.f;
        const float vy0 = ((unsigned)y0 <= 127u) ? 1.f : 0.f;
        const float vy1 = ((unsigned)(y0 + 1) <= 127u) ? 1.f : 0.f;

        s_off[g][cmb][0] = (y0c * 128 + x0c) * 512;
        s_off[g][cmb][1] = (y0c * 128 + x1c) * 512;
        s_off[g][cmb][2] = (y1c * 128 + x0c) * 512;
        s_off[g][cmb][3] = (y1c * 128 + x1c) * 512;
        s_c[g][cmb][0] = aw * (1.f - fx) * (1.f - fy) * vx0 * vy0;
        s_c[g][cmb][1] = aw * fx * (1.f - fy) * vx1 * vy0;
        s_c[g][cmb][2] = aw * (1.f - fx) * fy * vx0 * vy1;
        s_c[g][cmb][3] = aw * fx * fy * vx1 * vy1;
    }
    __syncthreads();

    const int half = t >> 7;
    const int h    = (t >> 4) & 7;
    const int dd   = t & 15;
    const char* vb = (const char*)vcomp + ((size_t)bq * NQ_ * 256 + h * 32 + dd * 2) * 2;

    #pragma unroll
    for (int it = 0; it < 4; ++it) {
        const int g = it * 2 + half;
        float a0 = 0.f, a1 = 0.f;
        #pragma unroll
        for (int p = 0; p < 4; ++p) {
            const int cmb = h * 4 + p;
            #pragma unroll
            for (int k = 0; k < 4; ++k) {
                const unsigned u = *(const unsigned*)(vb + s_off[g][cmb][k]);
                const float c = s_c[g][cmb][k];
                a0 += c * __uint_as_float(u << 16);
                a1 += c * __uint_as_float(u & 0xffff0000u);
            }
        }
        const int r = r0 + g;
        const unsigned o = (unsigned)(unsigned short)f2bf(a0)
                         | ((unsigned)(unsigned short)f2bf(a1) << 16);
        *(unsigned*)&msda[(size_t)r * 256 + h * 32 + dd * 2] = o;
    }
}

// ---------------------------------------------------------------------------
extern "C" void kernel_launch(void* const* d_in, const int* in_sizes, int n_in,
                              void* d_out, int out_size, void* d_ws, size_t ws_size,
                              hipStream_t stream) {
    const float* q      = (const float*)d_in[0];
    const float* b_out  = (const float*)d_in[8];
    const float* b1     = (const float*)d_in[10];
    const float* b2     = (const float*)d_in[12];
    const float* gamma  = (const float*)d_in[13];
    const float* beta   = (const float*)d_in[14];

    float* out = (float*)d_out;

    char* w = (char*)d_ws;
    float* pm    = (float*)w; w += (size_t)RTOT_ * 128 * 4;      // 16.8 MB
    short* vcomp = (short*)w; w += (size_t)RTOT_ * 256 * 2;      // 16.8 MB
    short* qbf   = (short*)w; w += (size_t)RTOT_ * EMBED_ * 2;   // 16.8 MB
    short* msda  = (short*)w; w += (size_t)RTOT_ * EMBED_ * 2;   // 16.8 MB
    short* xbf   = (short*)w; w += (size_t)RTOT_ * EMBED_ * 2;   // 16.8 MB
    short* hid   = (short*)w; w += (size_t)RTOT_ * FFN_ * 2;     // 33.6 MB
    short* WcatT = (short*)w; w += WCAT_ELEMS * 2;
    short* WoutT = (short*)w; w += WOUT_ELEMS * 2;
    short* W1T   = (short*)w; w += W1_ELEMS * 2;
    short* W2T   = (short*)w; w += W2_ELEMS * 2;
    float* bcat  = (float*)w; w += NCATP_ * 4;

    // q->bf16 + weight prep (one launch)
    prep_all<<<CVT_BLOCKS + PREP_BLOCKS, 256, 0, stream>>>(
        q, qbf,
        (const float*)d_in[5], (const float*)d_in[1], (const float*)d_in[3],
        (const float*)d_in[6], (const float*)d_in[2], (const float*)d_in[4],
        (const float*)d_in[7], (const float*)d_in[9], (const float*)d_in[11],
        WcatT, WoutT, W1T, W2T, bcat);

    // proj: vcomp (bf16 value) + pm (f32 meta)   (32768 x 384 x 256)
    gemm_mfma<EP_SPLIT><<<dim3(NCATP_ / 128, RTOT_ / 128), 256, 0, stream>>>(
        qbf, WcatT, bcat, nullptr, pm, vcomp, RTOT_, NCATP_, EMBED_);

    // MSDA sampling -> msda (bf16)
    msda_sample<<<RTOT_ / 8, 256, 0, stream>>>(pm, vcomp, msda);

    // xbf = bf16(msda @ W_out + b_out + 2q)   (32768 x 256 x 256)
    gemm_mfma<EP_ADD2Q_BF16><<<dim3(EMBED_ / 128, RTOT_ / 128), 256, 0, stream>>>(
        msda, WoutT, b_out, qbf, nullptr, xbf, RTOT_, EMBED_, EMBED_);

    // hid = relu(x @ W1 + b1)                 (32768 x 512 x 256)
    gemm_mfma<EP_RELU_BF16><<<dim3(FFN_ / 128, RTOT_ / 128), 256, 0, stream>>>(
        xbf, W1T, b1, nullptr, nullptr, hid, RTOT_, FFN_, EMBED_);

    // out = x + LN(hid @ W2 + b2)*gamma + beta (32768 x 256 x 512, fused LN)
    gemm_ln<<<RTOT_ / 64, 256, 0, stream>>>(
        hid, W2T, b2, xbf, gamma, beta, out, RTOT_, FFN_);
}

// Round 8
// 103.298 us; speedup vs baseline: 1.0252x; 1.0252x over previous
//
#include <hip/hip_runtime.h>
#include <hip/hip_bf16.h>
#include <cstddef>
#include <cstdint>

#define B_      2
#define QD_     128
#define NQ_     (QD_ * QD_)          // 16384
#define EMBED_  256
#define HEADS_  8
#define POINTS_ 4
#define FFN_    512
#define RTOT_   (B_ * NQ_)           // 32768
#define NCATP_  384                  // 352 real cols padded to 384

using bf16x8 = __attribute__((ext_vector_type(8))) short;   // 8 bf16 = 4 VGPRs
using f32x4  = __attribute__((ext_vector_type(4))) float;   // MFMA accumulator

__device__ __forceinline__ short f2bf(float f) {
    unsigned u = __float_as_uint(f);
    u += 0x7FFFu + ((u >> 16) & 1u);          // round-to-nearest-even
    return (short)(u >> 16);
}
__device__ __forceinline__ float bf2f(short s) {
    return __uint_as_float(((unsigned)(unsigned short)s) << 16);
}

#define GLDS(gp, lp) __builtin_amdgcn_global_load_lds( \
        (const __attribute__((address_space(1))) void*)(gp), \
        (__attribute__((address_space(3))) void*)(lp), 16, 0, 0)

#define WCAT_ELEMS  (NCATP_ * 256)
#define WOUT_ELEMS  (256 * 256)
#define W1_ELEMS    (512 * 256)
#define W2_ELEMS    (256 * 512)
#define PREP_TOTAL  (WCAT_ELEMS + WOUT_ELEMS + W1_ELEMS + W2_ELEMS)   // 425984
#define CVT_BLOCKS  (RTOT_ * EMBED_ / 8 / 256)                         // 4096
#define PREP_BLOCKS ((PREP_TOTAL + 255) / 256)                         // 1664

// ---------------------------------------------------------------------------
// Fused prep: q->bf16 (blocks [0,4096)) + weight transpose/concat (rest).
// ---------------------------------------------------------------------------
__global__ __launch_bounds__(256) void prep_all(
        const float* __restrict__ q, short* __restrict__ qbf,
        const float* __restrict__ Wv, const float* __restrict__ Wo,
        const float* __restrict__ Wa, const float* __restrict__ bv,
        const float* __restrict__ bo, const float* __restrict__ ba,
        const float* __restrict__ W_out, const float* __restrict__ W1,
        const float* __restrict__ W2,
        short* __restrict__ WcatT, short* __restrict__ WoutT,
        short* __restrict__ W1T, short* __restrict__ W2T,
        float* __restrict__ bcat) {
    const int b = blockIdx.x;
    if (b < CVT_BLOCKS) {
        const size_t i = (size_t)b * 256 + threadIdx.x;
        const float4 f0 = *(const float4*)(q + i * 8);
        const float4 f1 = *(const float4*)(q + i * 8 + 4);
        bf16x8 v;
        v[0] = f2bf(f0.x); v[1] = f2bf(f0.y); v[2] = f2bf(f0.z); v[3] = f2bf(f0.w);
        v[4] = f2bf(f1.x); v[5] = f2bf(f1.y); v[6] = f2bf(f1.z); v[7] = f2bf(f1.w);
        *(bf16x8*)(qbf + i * 8) = v;
        return;
    }
    int idx = (b - CVT_BLOCKS) * 256 + threadIdx.x;
    if (idx < WCAT_ELEMS) {
        int c = idx >> 8, k = idx & 255;
        float v = 0.f;
        if (c < 256)      v = Wv[k * 256 + c];
        else if (c < 320) v = Wo[k * 64 + (c - 256)];
        else if (c < 352) v = Wa[k * 32 + (c - 320)];
        WcatT[idx] = f2bf(v);
    } else if (idx < WCAT_ELEMS + WOUT_ELEMS) {
        int j = idx - WCAT_ELEMS; int c = j >> 8, k = j & 255;
        WoutT[j] = f2bf(W_out[k * 256 + c]);
    } else if (idx < WCAT_ELEMS + WOUT_ELEMS + W1_ELEMS) {
        int j = idx - (WCAT_ELEMS + WOUT_ELEMS); int c = j >> 8, k = j & 255;
        W1T[j] = f2bf(W1[k * 512 + c]);
    } else if (idx < PREP_TOTAL) {
        int j = idx - (WCAT_ELEMS + WOUT_ELEMS + W1_ELEMS); int c = j >> 9, k = j & 511;
        W2T[j] = f2bf(W2[k * 256 + c]);
    }
    if (idx < NCATP_) {
        float v = 0.f;
        if (idx < 256)      v = bv[idx];
        else if (idx < 320) v = bo[idx - 256];
        else if (idx < 352) v = ba[idx - 320];
        bcat[idx] = v;
    }
}

// ---------------------------------------------------------------------------
// bf16 MFMA GEMM, 2-phase double-buffered (used for the proj GEMM only).
// BM=BN=128, BK=64, 4 waves (2x2), 64x64/wave, 16x16x32 MFMA.
// ---------------------------------------------------------------------------
enum { EP_SPLIT = 3 };

template <int EP>
__global__ __launch_bounds__(256) void gemm_mfma(
        const short* __restrict__ A,            // [M][K] bf16
        const short* __restrict__ Bt,           // [N][K] bf16
        const float* __restrict__ bias,         // [N]
        float* __restrict__ Cf,                 // pm (SPLIT)
        short* __restrict__ Cb,                 // vcomp (SPLIT)
        int M, int N, int K) {
    __shared__ __align__(16) short As[2][128 * 64];
    __shared__ __align__(16) short Bs[2][128 * 64];

    const int t    = threadIdx.x;
    const int ln   = t & 63;
    const int w    = t >> 6;
    const int wr   = w >> 1;
    const int wc   = w & 1;
    const int lrow = ln & 15;
    const int lkg  = ln >> 4;

    const int gx   = gridDim.x;
    const int nwg  = gx * gridDim.y;
    const int flat = blockIdx.y * gx + blockIdx.x;
    const int q8   = nwg >> 3;
    const int swz  = (flat & 7) * q8 + (flat >> 3);
    const int row0 = (swz / gx) * 128;
    const int col0 = (swz % gx) * 128;

    f32x4 acc[4][4] = {};

    auto stage = [&](int buf, int k0) {
        #pragma unroll
        for (int j = 0; j < 4; ++j) {
            const int c0 = (w * 4 + j) * 64;
            const int c  = c0 + ln;
            const int r  = c >> 3;
            const int s  = (c & 7) ^ (r & 7);
            GLDS(A  + (size_t)(row0 + r) * K + (k0 + s * 8), &As[buf][c0 * 8]);
            GLDS(Bt + (size_t)(col0 + r) * K + (k0 + s * 8), &Bs[buf][c0 * 8]);
        }
    };

    stage(0, 0);
    __syncthreads();
    int cur = 0;
    for (int k0 = 0; k0 < K; k0 += 64) {
        if (k0 + 64 < K) stage(cur ^ 1, k0 + 64);
        #pragma unroll
        for (int ks = 0; ks < 2; ++ks) {
            const int slot = ((ks * 4 + lkg) ^ (lrow & 7)) * 8;
            bf16x8 af[4], bfr[4];
            #pragma unroll
            for (int m = 0; m < 4; ++m)
                af[m] = *(const bf16x8*)&As[cur][(wr * 64 + m * 16 + lrow) * 64 + slot];
            #pragma unroll
            for (int n = 0; n < 4; ++n)
                bfr[n] = *(const bf16x8*)&Bs[cur][(wc * 64 + n * 16 + lrow) * 64 + slot];
            #pragma unroll
            for (int m = 0; m < 4; ++m)
                #pragma unroll
                for (int n = 0; n < 4; ++n)
                    acc[m][n] = __builtin_amdgcn_mfma_f32_16x16x32_bf16(
                        af[m], bfr[n], acc[m][n], 0, 0, 0);
        }
        __syncthreads();
        cur ^= 1;
    }

    const int orow = (ln >> 4) * 4;
    const int ocol = ln & 15;
    #pragma unroll
    for (int m = 0; m < 4; ++m) {
        #pragma unroll
        for (int n = 0; n < 4; ++n) {
            const int col = col0 + wc * 64 + n * 16 + ocol;
            const float bv = bias[col];
            #pragma unroll
            for (int rr = 0; rr < 4; ++rr) {
                const int row = row0 + wr * 64 + m * 16 + orow + rr;
                float v = acc[m][n][rr] + bv;
                if (col < 256) Cb[(size_t)row * 256 + col] = f2bf(v);
                else           Cf[(size_t)row * 128 + (col - 256)] = v;
            }
        }
    }
}

// ---------------------------------------------------------------------------
// Fused out-proj + FFN-GEMM1:
//   x   = msda @ W_out + b_out + 2q   -> xbf (global) + xs (LDS)
//   hid = relu(x @ W1 + b1)           -> hid (global)
// One block = 128 rows, 512 threads = 8 waves (2 row-halves x 4 col-groups).
// xs keeps x in the GLDS-compatible swizzled layout so phase 2 reads it
// exactly like a staged tile. W_out/W1 tiles stream from L2.
// LDS = 64 (xs) + 48 (stage) = 112 KB -> 1 block/CU, grid 256 = full chip.
// ---------------------------------------------------------------------------
__global__ __launch_bounds__(512) void gemm_x_ffn1(
        const short* __restrict__ msda,         // [M][256] bf16
        const short* __restrict__ WoutT,        // [256][256] bf16
        const float* __restrict__ b_out,        // [256]
        const short* __restrict__ qbf,          // [M][256] bf16 (residual 2q)
        const short* __restrict__ W1T,          // [512][256] bf16
        const float* __restrict__ b1,           // [512]
        short* __restrict__ xbf,                // out [M][256] bf16
        short* __restrict__ hid) {              // out [M][512] bf16
    __shared__ __align__(16) short xs[128 * 256];   // 64 KB, 4 sections [128][64]
    __shared__ __align__(16) short stg[128 * 192];  // 48 KB staging
    short* As = stg;                 // [128][64] 16 KB (phase 1 A)
    short* Bs = stg + 128 * 64;      // [256][64] 32 KB (phase 1/2 B)

    const int t    = threadIdx.x;
    const int ln   = t & 63;
    const int w    = t >> 6;            // 0..7
    const int wr   = w >> 2;            // 0..1 row half
    const int wc   = w & 3;             // 0..3 col group
    const int lrow = ln & 15;
    const int lkg  = ln >> 4;
    const int row0 = blockIdx.x * 128;
    const int orow = lkg * 4;
    const int ocol = lrow;

    // ================= phase 1: x = msda @ WoutT^T + b_out + 2q ===========
    f32x4 acc[4][4] = {};
    for (int kt = 0; kt < 4; ++kt) {
        #pragma unroll
        for (int j = 0; j < 2; ++j) {           // A: 1024 chunks / 512 thr
            const int c0 = (w * 2 + j) * 64;
            const int cc = c0 + ln;
            const int r  = cc >> 3;
            const int s  = (cc & 7) ^ (r & 7);
            GLDS(msda + (size_t)(row0 + r) * 256 + kt * 64 + s * 8, &As[c0 * 8]);
        }
        #pragma unroll
        for (int j = 0; j < 4; ++j) {           // B: 2048 chunks / 512 thr
            const int c0 = (w * 4 + j) * 64;
            const int cc = c0 + ln;
            const int r  = cc >> 3;
            const int s  = (cc & 7) ^ (r & 7);
            GLDS(WoutT + (size_t)r * 256 + kt * 64 + s * 8, &Bs[c0 * 8]);
        }
        __syncthreads();
        #pragma unroll
        for (int ks = 0; ks < 2; ++ks) {
            const int slot = ((ks * 4 + lkg) ^ (lrow & 7)) * 8;
            bf16x8 af[4], bfr[4];
            #pragma unroll
            for (int m = 0; m < 4; ++m)
                af[m] = *(const bf16x8*)&As[(wr * 64 + m * 16 + lrow) * 64 + slot];
            #pragma unroll
            for (int n = 0; n < 4; ++n)
                bfr[n] = *(const bf16x8*)&Bs[(wc * 64 + n * 16 + lrow) * 64 + slot];
            #pragma unroll
            for (int m = 0; m < 4; ++m)
                #pragma unroll
                for (int n = 0; n < 4; ++n)
                    acc[m][n] = __builtin_amdgcn_mfma_f32_16x16x32_bf16(
                        af[m], bfr[n], acc[m][n], 0, 0, 0);
        }
        __syncthreads();
    }

    // epilogue 1: bias + 2q residual; write xbf (global) and xs (LDS, swizzled)
    #pragma unroll
    for (int m = 0; m < 4; ++m) {
        #pragma unroll
        for (int n = 0; n < 4; ++n) {
            const int kk  = n * 16 + ocol;           // col within section
            const int col = wc * 64 + kk;            // section = wc
            const float bv = b_out[col];
            #pragma unroll
            for (int rr = 0; rr < 4; ++rr) {
                const int row = wr * 64 + m * 16 + orow + rr;
                float v = acc[m][n][rr] + bv
                        + 2.f * bf2f(qbf[(size_t)(row0 + row) * 256 + col]);
                const short bb = f2bf(v);
                xbf[(size_t)(row0 + row) * 256 + col] = bb;
                xs[wc * 8192 + row * 64 + ((kk >> 3) ^ (row & 7)) * 8 + (kk & 7)] = bb;
            }
        }
    }
    __syncthreads();

    // ================= phase 2: hid = relu(xs @ W1T^T + b1) ================
    #pragma unroll 1
    for (int p = 0; p < 2; ++p) {               // two 256-col passes of N=512
        f32x4 acc2[4][4] = {};
        for (int kt = 0; kt < 4; ++kt) {
            #pragma unroll
            for (int j = 0; j < 4; ++j) {       // W1 tile [256][64]
                const int c0 = (w * 4 + j) * 64;
                const int cc = c0 + ln;
                const int r  = cc >> 3;
                const int s  = (cc & 7) ^ (r & 7);
                GLDS(W1T + (size_t)(p * 256 + r) * 256 + kt * 64 + s * 8, &Bs[c0 * 8]);
            }
            __syncthreads();
            #pragma unroll
            for (int ks = 0; ks < 2; ++ks) {
                const int slot = ((ks * 4 + lkg) ^ (lrow & 7)) * 8;
                bf16x8 af[4], bfr[4];
                #pragma unroll
                for (int m = 0; m < 4; ++m)
                    af[m] = *(const bf16x8*)&xs[kt * 8192 + (wr * 64 + m * 16 + lrow) * 64 + slot];
                #pragma unroll
                for (int n = 0; n < 4; ++n)
                    bfr[n] = *(const bf16x8*)&Bs[(wc * 64 + n * 16 + lrow) * 64 + slot];
                #pragma unroll
                for (int m = 0; m < 4; ++m)
                    #pragma unroll
                    for (int n = 0; n < 4; ++n)
                        acc2[m][n] = __builtin_amdgcn_mfma_f32_16x16x32_bf16(
                            af[m], bfr[n], acc2[m][n], 0, 0, 0);
            }
            __syncthreads();
        }
        // epilogue 2: relu + bias -> hid
        #pragma unroll
        for (int m = 0; m < 4; ++m) {
            #pragma unroll
            for (int n = 0; n < 4; ++n) {
                const int col = p * 256 + wc * 64 + n * 16 + ocol;
                const float bv = b1[col];
                #pragma unroll
                for (int rr = 0; rr < 4; ++rr) {
                    const int row = wr * 64 + m * 16 + orow + rr;
                    hid[(size_t)(row0 + row) * 512 + col] =
                        f2bf(fmaxf(acc2[m][n][rr] + bv, 0.f));
                }
            }
        }
    }
}

// ---------------------------------------------------------------------------
// Fused W2 GEMM + LayerNorm + residual: out = x + LN(hid@W2 + b2)*g + beta
// BM=64 rows, BN=256 (full row), BK=64, 256 threads = 4 waves side-by-side.
// ---------------------------------------------------------------------------
__global__ __launch_bounds__(256) void gemm_ln(
        const short* __restrict__ A,            // hid [M][512] bf16
        const short* __restrict__ Bt,           // W2T [256][512] bf16
        const float* __restrict__ bias,         // b2
        const short* __restrict__ xres,         // xbf [M][256] bf16
        const float* __restrict__ gamma, const float* __restrict__ beta,
        float* __restrict__ out, int M, int K) {
    __shared__ __align__(16) short As[2][64 * 64];    // 8 KB x2
    __shared__ __align__(16) short Bs[256 * 64];      // 32 KB
    __shared__ float red[64][4][2];                   // 2 KB

    const int t    = threadIdx.x;
    const int ln   = t & 63;
    const int w    = t >> 6;            // 0..3 col group
    const int lrow = ln & 15;
    const int lkg  = ln >> 4;
    const int row0 = blockIdx.x * 64;

    f32x4 acc[4][4] = {};

    auto stage_a = [&](int buf, int k0) {
        #pragma unroll
        for (int j = 0; j < 2; ++j) {
            const int c0 = (w * 2 + j) * 64;
            const int c  = c0 + ln;
            const int r  = c >> 3;
            const int s  = (c & 7) ^ (r & 7);
            GLDS(A + (size_t)(row0 + r) * K + (k0 + s * 8), &As[buf][c0 * 8]);
        }
    };
    auto stage_b = [&](int k0) {
        #pragma unroll
        for (int j = 0; j < 8; ++j) {
            const int c0 = (w * 8 + j) * 64;
            const int c  = c0 + ln;
            const int r  = c >> 3;
            const int s  = (c & 7) ^ (r & 7);
            GLDS(Bt + (size_t)r * K + (k0 + s * 8), &Bs[c0 * 8]);
        }
    };

    stage_a(0, 0);
    stage_b(0);
    __syncthreads();
    int buf = 0;
    for (int kt = 0; kt < 8; ++kt) {
        if (kt < 7) stage_a(buf ^ 1, kt * 64 + 64);
        #pragma unroll
        for (int ks = 0; ks < 2; ++ks) {
            const int slot = ((ks * 4 + lkg) ^ (lrow & 7)) * 8;
            bf16x8 af[4], bfr[4];
            #pragma unroll
            for (int m = 0; m < 4; ++m)
                af[m] = *(const bf16x8*)&As[buf][(m * 16 + lrow) * 64 + slot];
            #pragma unroll
            for (int n = 0; n < 4; ++n)
                bfr[n] = *(const bf16x8*)&Bs[(w * 64 + n * 16 + lrow) * 64 + slot];
            #pragma unroll
            for (int m = 0; m < 4; ++m)
                #pragma unroll
                for (int n = 0; n < 4; ++n)
                    acc[m][n] = __builtin_amdgcn_mfma_f32_16x16x32_bf16(
                        af[m], bfr[n], acc[m][n], 0, 0, 0);
        }
        __syncthreads();
        if (kt < 7) {
            stage_b(kt * 64 + 64);
            __syncthreads();
        }
        buf ^= 1;
    }

    const int orow = lkg * 4;
    const int ocol = lrow;

    #pragma unroll
    for (int n = 0; n < 4; ++n) {
        const float bv = bias[w * 64 + n * 16 + ocol];
        #pragma unroll
        for (int m = 0; m < 4; ++m)
            #pragma unroll
            for (int rr = 0; rr < 4; ++rr)
                acc[m][n][rr] += bv;
    }

    #pragma unroll
    for (int m = 0; m < 4; ++m) {
        #pragma unroll
        for (int rr = 0; rr < 4; ++rr) {
            float s = 0.f, sq = 0.f;
            #pragma unroll
            for (int n = 0; n < 4; ++n) {
                const float v = acc[m][n][rr];
                s += v; sq += v * v;
            }
            #pragma unroll
            for (int o = 1; o < 16; o <<= 1) {
                s  += __shfl_xor(s, o, 64);
                sq += __shfl_xor(sq, o, 64);
            }
            if (ocol == 0) {
                const int row = m * 16 + orow + rr;
                red[row][w][0] = s;
                red[row][w][1] = sq;
            }
        }
    }
    __syncthreads();

    #pragma unroll
    for (int m = 0; m < 4; ++m) {
        #pragma unroll
        for (int rr = 0; rr < 4; ++rr) {
            const int row = m * 16 + orow + rr;
            const float S  = red[row][0][0] + red[row][1][0] + red[row][2][0] + red[row][3][0];
            const float SQ = red[row][0][1] + red[row][1][1] + red[row][2][1] + red[row][3][1];
            const float mean = S * (1.0f / 256.0f);
            const float var  = SQ * (1.0f / 256.0f) - mean * mean;
            const float rs   = rsqrtf(var + 1e-5f);
            const size_t rbase = (size_t)(row0 + row) * 256;
            #pragma unroll
            for (int n = 0; n < 4; ++n) {
                const int col = w * 64 + n * 16 + ocol;
                out[rbase + col] = bf2f(xres[rbase + col])
                                 + (acc[m][n][rr] - mean) * rs * gamma[col] + beta[col];
            }
        }
    }
}

// ---------------------------------------------------------------------------
// MSDA sampler, two-phase (unchanged).
// ---------------------------------------------------------------------------
__global__ __launch_bounds__(256) void msda_sample(
        const float* __restrict__ pm, const short* __restrict__ vcomp,
        short* __restrict__ msda) {
    __shared__ int   s_off[8][32][4];
    __shared__ float s_c[8][32][4];

    const int t  = threadIdx.x;
    const int r0 = blockIdx.x * 8;
    const int bq = r0 >> 14;

    {
        const int g = t >> 5, cmb = t & 31, h = cmb >> 2, p = cmb & 3;
        const int r = r0 + g;
        const int n = r & (NQ_ - 1);
        const int gi = n >> 7, gj = n & 127;
        const float* pr = pm + (size_t)r * 128;

        const float l0 = pr[64 + h * 4 + 0], l1 = pr[64 + h * 4 + 1];
        const float l2 = pr[64 + h * 4 + 2], l3 = pr[64 + h * 4 + 3];
        const float mx = fmaxf(fmaxf(l0, l1), fmaxf(l2, l3));
        const float sum = expf(l0 - mx) + expf(l1 - mx) + expf(l2 - mx) + expf(l3 - mx);
        const float lp = pr[64 + h * 4 + p];
        const float aw = expf(lp - mx) / sum;

        const float ox = pr[h * 8 + p * 2 + 0];
        const float oy = pr[h * 8 + p * 2 + 1];
        const float px = (gj * (1.0f / 127.0f) + ox * (1.0f / 128.0f)) * 128.0f - 0.5f;
        const float py = (gi * (1.0f / 127.0f) + oy * (1.0f / 128.0f)) * 128.0f - 0.5f;
        const float x0f = floorf(px), y0f = floorf(py);
        const int   x0 = (int)x0f, y0 = (int)y0f;
        const float fx = px - x0f, fy = py - y0f;
        const int x0c = min(max(x0, 0), 127), x1c = min(max(x0 + 1, 0), 127);
        const int y0c = min(max(y0, 0), 127), y1c = min(max(y0 + 1, 0), 127);
        const float vx0 = ((unsigned)x0 <= 127u) ? 1.f : 0.f;
        const float vx1 = ((unsigned)(x0 + 1) <= 127u) ? 1.f : 0.f;
        const float vy0 = ((unsigned)y0 <= 127u) ? 1.f : 0.f;
        const float vy1 = ((unsigned)(y0 + 1) <= 127u) ? 1.f : 0.f;

        s_off[g][cmb][0] = (y0c * 128 + x0c) * 512;
        s_off[g][cmb][1] = (y0c * 128 + x1c) * 512;
        s_off[g][cmb][2] = (y1c * 128 + x0c) * 512;
        s_off[g][cmb][3] = (y1c * 128 + x1c) * 512;
        s_c[g][cmb][0] = aw * (1.f - fx) * (1.f - fy) * vx0 * vy0;
        s_c[g][cmb][1] = aw * fx * (1.f - fy) * vx1 * vy0;
        s_c[g][cmb][2] = aw * (1.f - fx) * fy * vx0 * vy1;
        s_c[g][cmb][3] = aw * fx * fy * vx1 * vy1;
    }
    __syncthreads();

    const int half = t >> 7;
    const int h    = (t >> 4) & 7;
    const int dd   = t & 15;
    const char* vb = (const char*)vcomp + ((size_t)bq * NQ_ * 256 + h * 32 + dd * 2) * 2;

    #pragma unroll
    for (int it = 0; it < 4; ++it) {
        const int g = it * 2 + half;
        float a0 = 0.f, a1 = 0.f;
        #pragma unroll
        for (int p = 0; p < 4; ++p) {
            const int cmb = h * 4 + p;
            #pragma unroll
            for (int k = 0; k < 4; ++k) {
                const unsigned u = *(const unsigned*)(vb + s_off[g][cmb][k]);
                const float c = s_c[g][cmb][k];
                a0 += c * __uint_as_float(u << 16);
                a1 += c * __uint_as_float(u & 0xffff0000u);
            }
        }
        const int r = r0 + g;
        const unsigned o = (unsigned)(unsigned short)f2bf(a0)
                         | ((unsigned)(unsigned short)f2bf(a1) << 16);
        *(unsigned*)&msda[(size_t)r * 256 + h * 32 + dd * 2] = o;
    }
}

// ---------------------------------------------------------------------------
extern "C" void kernel_launch(void* const* d_in, const int* in_sizes, int n_in,
                              void* d_out, int out_size, void* d_ws, size_t ws_size,
                              hipStream_t stream) {
    const float* q      = (const float*)d_in[0];
    const float* b_out  = (const float*)d_in[8];
    const float* b1     = (const float*)d_in[10];
    const float* b2     = (const float*)d_in[12];
    const float* gamma  = (const float*)d_in[13];
    const float* beta   = (const float*)d_in[14];

    float* out = (float*)d_out;

    char* w = (char*)d_ws;
    float* pm    = (float*)w; w += (size_t)RTOT_ * 128 * 4;      // 16.8 MB
    short* vcomp = (short*)w; w += (size_t)RTOT_ * 256 * 2;      // 16.8 MB
    short* qbf   = (short*)w; w += (size_t)RTOT_ * EMBED_ * 2;   // 16.8 MB
    short* msda  = (short*)w; w += (size_t)RTOT_ * EMBED_ * 2;   // 16.8 MB
    short* xbf   = (short*)w; w += (size_t)RTOT_ * EMBED_ * 2;   // 16.8 MB
    short* hid   = (short*)w; w += (size_t)RTOT_ * FFN_ * 2;     // 33.6 MB
    short* WcatT = (short*)w; w += WCAT_ELEMS * 2;
    short* WoutT = (short*)w; w += WOUT_ELEMS * 2;
    short* W1T   = (short*)w; w += W1_ELEMS * 2;
    short* W2T   = (short*)w; w += W2_ELEMS * 2;
    float* bcat  = (float*)w; w += NCATP_ * 4;

    // q->bf16 + weight prep (one launch)
    prep_all<<<CVT_BLOCKS + PREP_BLOCKS, 256, 0, stream>>>(
        q, qbf,
        (const float*)d_in[5], (const float*)d_in[1], (const float*)d_in[3],
        (const float*)d_in[6], (const float*)d_in[2], (const float*)d_in[4],
        (const float*)d_in[7], (const float*)d_in[9], (const float*)d_in[11],
        WcatT, WoutT, W1T, W2T, bcat);

    // proj: vcomp (bf16 value) + pm (f32 meta)   (32768 x 384 x 256)
    gemm_mfma<EP_SPLIT><<<dim3(NCATP_ / 128, RTOT_ / 128), 256, 0, stream>>>(
        qbf, WcatT, bcat, pm, vcomp, RTOT_, NCATP_, EMBED_);

    // MSDA sampling -> msda (bf16)
    msda_sample<<<RTOT_ / 8, 256, 0, stream>>>(pm, vcomp, msda);

    // fused: xbf = bf16(msda@W_out + b_out + 2q); hid = relu(x@W1 + b1)
    gemm_x_ffn1<<<RTOT_ / 128, 512, 0, stream>>>(
        msda, WoutT, b_out, qbf, W1T, b1, xbf, hid);

    // out = x + LN(hid @ W2 + b2)*gamma + beta
    gemm_ln<<<RTOT_ / 64, 256, 0, stream>>>(
        hid, W2T, b2, xbf, gamma, beta, out, RTOT_, FFN_);
}

// Round 9
// 101.137 us; speedup vs baseline: 1.0472x; 1.0214x over previous
//
#include <hip/hip_runtime.h>
#include <hip/hip_bf16.h>
#include <cstddef>
#include <cstdint>

#define B_      2
#define QD_     128
#define NQ_     (QD_ * QD_)          // 16384
#define EMBED_  256
#define HEADS_  8
#define POINTS_ 4
#define FFN_    512
#define RTOT_   (B_ * NQ_)           // 32768
#define NCATP_  384                  // 352 real cols padded to 384

using bf16x8 = __attribute__((ext_vector_type(8))) short;   // 8 bf16 = 4 VGPRs
using f32x4  = __attribute__((ext_vector_type(4))) float;   // MFMA accumulator

__device__ __forceinline__ short f2bf(float f) {
    unsigned u = __float_as_uint(f);
    u += 0x7FFFu + ((u >> 16) & 1u);          // round-to-nearest-even
    return (short)(u >> 16);
}
__device__ __forceinline__ float bf2f(short s) {
    return __uint_as_float(((unsigned)(unsigned short)s) << 16);
}

#define GLDS(gp, lp) __builtin_amdgcn_global_load_lds( \
        (const __attribute__((address_space(1))) void*)(gp), \
        (__attribute__((address_space(3))) void*)(lp), 16, 0, 0)

#define WCAT_ELEMS  (NCATP_ * 256)
#define WOUT_ELEMS  (256 * 256)
#define W1_ELEMS    (512 * 256)
#define W2_ELEMS    (256 * 512)
#define PREP_TOTAL  (WCAT_ELEMS + WOUT_ELEMS + W1_ELEMS + W2_ELEMS)   // 425984
#define PREP_BLOCKS ((PREP_TOTAL + 255) / 256)                         // 1664

// ---------------------------------------------------------------------------
// Weight prep only: transpose/concat weights to bf16 [N][K] layouts.
// ---------------------------------------------------------------------------
__global__ __launch_bounds__(256) void prep_weights(
        const float* __restrict__ Wv, const float* __restrict__ Wo,
        const float* __restrict__ Wa, const float* __restrict__ bv,
        const float* __restrict__ bo, const float* __restrict__ ba,
        const float* __restrict__ W_out, const float* __restrict__ W1,
        const float* __restrict__ W2,
        short* __restrict__ WcatT, short* __restrict__ WoutT,
        short* __restrict__ W1T, short* __restrict__ W2T,
        float* __restrict__ bcat) {
    int idx = blockIdx.x * 256 + threadIdx.x;
    if (idx < WCAT_ELEMS) {
        int c = idx >> 8, k = idx & 255;
        float v = 0.f;
        if (c < 256)      v = Wv[k * 256 + c];
        else if (c < 320) v = Wo[k * 64 + (c - 256)];
        else if (c < 352) v = Wa[k * 32 + (c - 320)];
        WcatT[idx] = f2bf(v);
    } else if (idx < WCAT_ELEMS + WOUT_ELEMS) {
        int j = idx - WCAT_ELEMS; int c = j >> 8, k = j & 255;
        WoutT[j] = f2bf(W_out[k * 256 + c]);
    } else if (idx < WCAT_ELEMS + WOUT_ELEMS + W1_ELEMS) {
        int j = idx - (WCAT_ELEMS + WOUT_ELEMS); int c = j >> 8, k = j & 255;
        W1T[j] = f2bf(W1[k * 512 + c]);
    } else if (idx < PREP_TOTAL) {
        int j = idx - (WCAT_ELEMS + WOUT_ELEMS + W1_ELEMS); int c = j >> 9, k = j & 511;
        W2T[j] = f2bf(W2[k * 256 + c]);
    }
    if (idx < NCATP_) {
        float v = 0.f;
        if (idx < 256)      v = bv[idx];
        else if (idx < 320) v = bo[idx - 256];
        else if (idx < 352) v = ba[idx - 320];
        bcat[idx] = v;
    }
}

// ---------------------------------------------------------------------------
// Fused q-cvt + proj GEMM (A-resident):
//   qbf   = bf16(q)                         (each tile converted exactly once)
//   out   = q @ WcatT^T + bcat  ->  vcomp (cols<256, bf16) / pm (cols>=256, f32)
// One block = 128 rows x all 384 cols, 512 threads = 8 waves (2x4).
// A tile lives in LDS (64 KB, swizzled); Wcat B tiles stream from L2,
// double-buffered GLDS, 12 steps (3 N-chunks x 4 k-steps).
// ---------------------------------------------------------------------------
__global__ __launch_bounds__(512) void gemm1_fused(
        const float* __restrict__ q,            // [M][256] f32
        const short* __restrict__ WcatT,        // [384][256] bf16
        const float* __restrict__ bcat,         // [384]
        short* __restrict__ qbf,                // out [M][256] bf16
        short* __restrict__ vcomp,              // out [M][256] bf16 (value)
        float* __restrict__ pm) {               // out [M][128] f32 (off|logits)
    __shared__ __align__(16) short xs[128 * 256];   // 64 KB A (4 sect [128][64])
    __shared__ __align__(16) short Bs[2][128 * 64]; // 16 KB x2 B dbuf

    const int t    = threadIdx.x;
    const int ln   = t & 63;
    const int w    = t >> 6;            // 0..7
    const int wr   = w >> 2;            // 0..1 row half
    const int wc   = w & 3;             // 0..3 col group (32 cols)
    const int lrow = ln & 15;
    const int lkg  = ln >> 4;
    const int row0 = blockIdx.x * 128;
    const int orow = lkg * 4;
    const int ocol = lrow;

    auto stage_b = [&](int step, int buf) {     // step = p*4 + kt
        const int p  = step >> 2;
        const int kt = step & 3;
        #pragma unroll
        for (int j = 0; j < 2; ++j) {           // 1024 chunks / 512 thr
            const int c0 = (w * 2 + j) * 64;
            const int c  = c0 + ln;
            const int r  = c >> 3;
            const int s  = (c & 7) ^ (r & 7);
            GLDS(WcatT + (size_t)(p * 128 + r) * 256 + kt * 64 + s * 8,
                 &Bs[buf][c0 * 8]);
        }
    };

    // ---- B(step 0) in flight, then A: q f32 -> bf16 -> xs + qbf ----
    stage_b(0, 0);
    #pragma unroll
    for (int j = 0; j < 8; ++j) {
        const int c = t + 512 * j;              // chunk 0..4095
        const int r = c >> 5;                   // row in tile
        const int s = c & 31;                   // 8-elem chunk in row
        const float* qp = q + (size_t)(row0 + r) * 256 + s * 8;
        const float4 f0 = *(const float4*)qp;
        const float4 f1 = *(const float4*)(qp + 4);
        bf16x8 v;
        v[0] = f2bf(f0.x); v[1] = f2bf(f0.y); v[2] = f2bf(f0.z); v[3] = f2bf(f0.w);
        v[4] = f2bf(f1.x); v[5] = f2bf(f1.y); v[6] = f2bf(f1.z); v[7] = f2bf(f1.w);
        *(bf16x8*)&qbf[(size_t)(row0 + r) * 256 + s * 8] = v;
        const int kt = s >> 3, sc = s & 7;
        *(bf16x8*)&xs[kt * 8192 + r * 64 + (sc ^ (r & 7)) * 8] = v;
    }
    __syncthreads();

    f32x4 acc[4][2] = {};
    const f32x4 zero = {0.f, 0.f, 0.f, 0.f};

    int buf = 0;
    #pragma unroll 1
    for (int step = 0; step < 12; ++step) {
        if (step < 11) stage_b(step + 1, buf ^ 1);
        const int kt = step & 3;
        #pragma unroll
        for (int ks = 0; ks < 2; ++ks) {
            const int slot = ((ks * 4 + lkg) ^ (lrow & 7)) * 8;
            bf16x8 af[4], bfr[2];
            #pragma unroll
            for (int m = 0; m < 4; ++m)
                af[m] = *(const bf16x8*)&xs[kt * 8192 + (wr * 64 + m * 16 + lrow) * 64 + slot];
            #pragma unroll
            for (int n = 0; n < 2; ++n)
                bfr[n] = *(const bf16x8*)&Bs[buf][(wc * 32 + n * 16 + lrow) * 64 + slot];
            #pragma unroll
            for (int m = 0; m < 4; ++m)
                #pragma unroll
                for (int n = 0; n < 2; ++n)
                    acc[m][n] = __builtin_amdgcn_mfma_f32_16x16x32_bf16(
                        af[m], bfr[n], acc[m][n], 0, 0, 0);
        }
        __syncthreads();
        if ((step & 3) == 3) {                  // N-chunk boundary: epilogue
            const int p = step >> 2;
            #pragma unroll
            for (int m = 0; m < 4; ++m) {
                #pragma unroll
                for (int n = 0; n < 2; ++n) {
                    const int gcol = p * 128 + wc * 32 + n * 16 + ocol;
                    const float bv = bcat[gcol];
                    #pragma unroll
                    for (int rr = 0; rr < 4; ++rr) {
                        const int row = wr * 64 + m * 16 + orow + rr;
                        const float v = acc[m][n][rr] + bv;
                        if (gcol < 256) {
                            vcomp[(size_t)(row0 + row) * 256 + gcol] = f2bf(v);
                        } else {
                            const int cc = gcol - 256;
                            if (cc < 96)
                                pm[(size_t)(row0 + row) * 128 + cc] = v;
                        }
                    }
                    acc[m][n] = zero;
                }
            }
        }
        buf ^= 1;
    }
}

// ---------------------------------------------------------------------------
// Fused out-proj + FFN-GEMM1 (unchanged from round 8).
// ---------------------------------------------------------------------------
__global__ __launch_bounds__(512) void gemm_x_ffn1(
        const short* __restrict__ msda,         // [M][256] bf16
        const short* __restrict__ WoutT,        // [256][256] bf16
        const float* __restrict__ b_out,        // [256]
        const short* __restrict__ qbf,          // [M][256] bf16 (residual 2q)
        const short* __restrict__ W1T,          // [512][256] bf16
        const float* __restrict__ b1,           // [512]
        short* __restrict__ xbf,                // out [M][256] bf16
        short* __restrict__ hid) {              // out [M][512] bf16
    __shared__ __align__(16) short xs[128 * 256];   // 64 KB
    __shared__ __align__(16) short stg[128 * 192];  // 48 KB staging
    short* As = stg;
    short* Bs = stg + 128 * 64;

    const int t    = threadIdx.x;
    const int ln   = t & 63;
    const int w    = t >> 6;
    const int wr   = w >> 2;
    const int wc   = w & 3;
    const int lrow = ln & 15;
    const int lkg  = ln >> 4;
    const int row0 = blockIdx.x * 128;
    const int orow = lkg * 4;
    const int ocol = lrow;

    // phase 1: x = msda @ WoutT^T + b_out + 2q
    f32x4 acc[4][4] = {};
    for (int kt = 0; kt < 4; ++kt) {
        #pragma unroll
        for (int j = 0; j < 2; ++j) {
            const int c0 = (w * 2 + j) * 64;
            const int cc = c0 + ln;
            const int r  = cc >> 3;
            const int s  = (cc & 7) ^ (r & 7);
            GLDS(msda + (size_t)(row0 + r) * 256 + kt * 64 + s * 8, &As[c0 * 8]);
        }
        #pragma unroll
        for (int j = 0; j < 4; ++j) {
            const int c0 = (w * 4 + j) * 64;
            const int cc = c0 + ln;
            const int r  = cc >> 3;
            const int s  = (cc & 7) ^ (r & 7);
            GLDS(WoutT + (size_t)r * 256 + kt * 64 + s * 8, &Bs[c0 * 8]);
        }
        __syncthreads();
        #pragma unroll
        for (int ks = 0; ks < 2; ++ks) {
            const int slot = ((ks * 4 + lkg) ^ (lrow & 7)) * 8;
            bf16x8 af[4], bfr[4];
            #pragma unroll
            for (int m = 0; m < 4; ++m)
                af[m] = *(const bf16x8*)&As[(wr * 64 + m * 16 + lrow) * 64 + slot];
            #pragma unroll
            for (int n = 0; n < 4; ++n)
                bfr[n] = *(const bf16x8*)&Bs[(wc * 64 + n * 16 + lrow) * 64 + slot];
            #pragma unroll
            for (int m = 0; m < 4; ++m)
                #pragma unroll
                for (int n = 0; n < 4; ++n)
                    acc[m][n] = __builtin_amdgcn_mfma_f32_16x16x32_bf16(
                        af[m], bfr[n], acc[m][n], 0, 0, 0);
        }
        __syncthreads();
    }

    #pragma unroll
    for (int m = 0; m < 4; ++m) {
        #pragma unroll
        for (int n = 0; n < 4; ++n) {
            const int kk  = n * 16 + ocol;
            const int col = wc * 64 + kk;
            const float bv = b_out[col];
            #pragma unroll
            for (int rr = 0; rr < 4; ++rr) {
                const int row = wr * 64 + m * 16 + orow + rr;
                float v = acc[m][n][rr] + bv
                        + 2.f * bf2f(qbf[(size_t)(row0 + row) * 256 + col]);
                const short bb = f2bf(v);
                xbf[(size_t)(row0 + row) * 256 + col] = bb;
                xs[wc * 8192 + row * 64 + ((kk >> 3) ^ (row & 7)) * 8 + (kk & 7)] = bb;
            }
        }
    }
    __syncthreads();

    // phase 2: hid = relu(xs @ W1T^T + b1)
    #pragma unroll 1
    for (int p = 0; p < 2; ++p) {
        f32x4 acc2[4][4] = {};
        for (int kt = 0; kt < 4; ++kt) {
            #pragma unroll
            for (int j = 0; j < 4; ++j) {
                const int c0 = (w * 4 + j) * 64;
                const int cc = c0 + ln;
                const int r  = cc >> 3;
                const int s  = (cc & 7) ^ (r & 7);
                GLDS(W1T + (size_t)(p * 256 + r) * 256 + kt * 64 + s * 8, &Bs[c0 * 8]);
            }
            __syncthreads();
            #pragma unroll
            for (int ks = 0; ks < 2; ++ks) {
                const int slot = ((ks * 4 + lkg) ^ (lrow & 7)) * 8;
                bf16x8 af[4], bfr[4];
                #pragma unroll
                for (int m = 0; m < 4; ++m)
                    af[m] = *(const bf16x8*)&xs[kt * 8192 + (wr * 64 + m * 16 + lrow) * 64 + slot];
                #pragma unroll
                for (int n = 0; n < 4; ++n)
                    bfr[n] = *(const bf16x8*)&Bs[(wc * 64 + n * 16 + lrow) * 64 + slot];
                #pragma unroll
                for (int m = 0; m < 4; ++m)
                    #pragma unroll
                    for (int n = 0; n < 4; ++n)
                        acc2[m][n] = __builtin_amdgcn_mfma_f32_16x16x32_bf16(
                            af[m], bfr[n], acc2[m][n], 0, 0, 0);
            }
            __syncthreads();
        }
        #pragma unroll
        for (int m = 0; m < 4; ++m) {
            #pragma unroll
            for (int n = 0; n < 4; ++n) {
                const int col = p * 256 + wc * 64 + n * 16 + ocol;
                const float bv = b1[col];
                #pragma unroll
                for (int rr = 0; rr < 4; ++rr) {
                    const int row = wr * 64 + m * 16 + orow + rr;
                    hid[(size_t)(row0 + row) * 512 + col] =
                        f2bf(fmaxf(acc2[m][n][rr] + bv, 0.f));
                }
            }
        }
    }
}

// ---------------------------------------------------------------------------
// Fused W2 GEMM + LayerNorm + residual (unchanged from round 8).
// ---------------------------------------------------------------------------
__global__ __launch_bounds__(256) void gemm_ln(
        const short* __restrict__ A,            // hid [M][512] bf16
        const short* __restrict__ Bt,           // W2T [256][512] bf16
        const float* __restrict__ bias,         // b2
        const short* __restrict__ xres,         // xbf [M][256] bf16
        const float* __restrict__ gamma, const float* __restrict__ beta,
        float* __restrict__ out, int M, int K) {
    __shared__ __align__(16) short As[2][64 * 64];
    __shared__ __align__(16) short Bs[256 * 64];
    __shared__ float red[64][4][2];

    const int t    = threadIdx.x;
    const int ln   = t & 63;
    const int w    = t >> 6;
    const int lrow = ln & 15;
    const int lkg  = ln >> 4;
    const int row0 = blockIdx.x * 64;

    f32x4 acc[4][4] = {};

    auto stage_a = [&](int buf, int k0) {
        #pragma unroll
        for (int j = 0; j < 2; ++j) {
            const int c0 = (w * 2 + j) * 64;
            const int c  = c0 + ln;
            const int r  = c >> 3;
            const int s  = (c & 7) ^ (r & 7);
            GLDS(A + (size_t)(row0 + r) * K + (k0 + s * 8), &As[buf][c0 * 8]);
        }
    };
    auto stage_b = [&](int k0) {
        #pragma unroll
        for (int j = 0; j < 8; ++j) {
            const int c0 = (w * 8 + j) * 64;
            const int c  = c0 + ln;
            const int r  = c >> 3;
            const int s  = (c & 7) ^ (r & 7);
            GLDS(Bt + (size_t)r * K + (k0 + s * 8), &Bs[c0 * 8]);
        }
    };

    stage_a(0, 0);
    stage_b(0);
    __syncthreads();
    int buf = 0;
    for (int kt = 0; kt < 8; ++kt) {
        if (kt < 7) stage_a(buf ^ 1, kt * 64 + 64);
        #pragma unroll
        for (int ks = 0; ks < 2; ++ks) {
            const int slot = ((ks * 4 + lkg) ^ (lrow & 7)) * 8;
            bf16x8 af[4], bfr[4];
            #pragma unroll
            for (int m = 0; m < 4; ++m)
                af[m] = *(const bf16x8*)&As[buf][(m * 16 + lrow) * 64 + slot];
            #pragma unroll
            for (int n = 0; n < 4; ++n)
                bfr[n] = *(const bf16x8*)&Bs[(w * 64 + n * 16 + lrow) * 64 + slot];
            #pragma unroll
            for (int m = 0; m < 4; ++m)
                #pragma unroll
                for (int n = 0; n < 4; ++n)
                    acc[m][n] = __builtin_amdgcn_mfma_f32_16x16x32_bf16(
                        af[m], bfr[n], acc[m][n], 0, 0, 0);
        }
        __syncthreads();
        if (kt < 7) {
            stage_b(kt * 64 + 64);
            __syncthreads();
        }
        buf ^= 1;
    }

    const int orow = lkg * 4;
    const int ocol = lrow;

    #pragma unroll
    for (int n = 0; n < 4; ++n) {
        const float bv = bias[w * 64 + n * 16 + ocol];
        #pragma unroll
        for (int m = 0; m < 4; ++m)
            #pragma unroll
            for (int rr = 0; rr < 4; ++rr)
                acc[m][n][rr] += bv;
    }

    #pragma unroll
    for (int m = 0; m < 4; ++m) {
        #pragma unroll
        for (int rr = 0; rr < 4; ++rr) {
            float s = 0.f, sq = 0.f;
            #pragma unroll
            for (int n = 0; n < 4; ++n) {
                const float v = acc[m][n][rr];
                s += v; sq += v * v;
            }
            #pragma unroll
            for (int o = 1; o < 16; o <<= 1) {
                s  += __shfl_xor(s, o, 64);
                sq += __shfl_xor(sq, o, 64);
            }
            if (ocol == 0) {
                const int row = m * 16 + orow + rr;
                red[row][w][0] = s;
                red[row][w][1] = sq;
            }
        }
    }
    __syncthreads();

    #pragma unroll
    for (int m = 0; m < 4; ++m) {
        #pragma unroll
        for (int rr = 0; rr < 4; ++rr) {
            const int row = m * 16 + orow + rr;
            const float S  = red[row][0][0] + red[row][1][0] + red[row][2][0] + red[row][3][0];
            const float SQ = red[row][0][1] + red[row][1][1] + red[row][2][1] + red[row][3][1];
            const float mean = S * (1.0f / 256.0f);
            const float var  = SQ * (1.0f / 256.0f) - mean * mean;
            const float rs   = rsqrtf(var + 1e-5f);
            const size_t rbase = (size_t)(row0 + row) * 256;
            #pragma unroll
            for (int n = 0; n < 4; ++n) {
                const int col = w * 64 + n * 16 + ocol;
                out[rbase + col] = bf2f(xres[rbase + col])
                                 + (acc[m][n][rr] - mean) * rs * gamma[col] + beta[col];
            }
        }
    }
}

// ---------------------------------------------------------------------------
// MSDA sampler, two-phase (unchanged).
// ---------------------------------------------------------------------------
__global__ __launch_bounds__(256) void msda_sample(
        const float* __restrict__ pm, const short* __restrict__ vcomp,
        short* __restrict__ msda) {
    __shared__ int   s_off[8][32][4];
    __shared__ float s_c[8][32][4];

    const int t  = threadIdx.x;
    const int r0 = blockIdx.x * 8;
    const int bq = r0 >> 14;

    {
        const int g = t >> 5, cmb = t & 31, h = cmb >> 2, p = cmb & 3;
        const int r = r0 + g;
        const int n = r & (NQ_ - 1);
        const int gi = n >> 7, gj = n & 127;
        const float* pr = pm + (size_t)r * 128;

        const float l0 = pr[64 + h * 4 + 0], l1 = pr[64 + h * 4 + 1];
        const float l2 = pr[64 + h * 4 + 2], l3 = pr[64 + h * 4 + 3];
        const float mx = fmaxf(fmaxf(l0, l1), fmaxf(l2, l3));
        const float sum = expf(l0 - mx) + expf(l1 - mx) + expf(l2 - mx) + expf(l3 - mx);
        const float lp = pr[64 + h * 4 + p];
        const float aw = expf(lp - mx) / sum;

        const float ox = pr[h * 8 + p * 2 + 0];
        const float oy = pr[h * 8 + p * 2 + 1];
        const float px = (gj * (1.0f / 127.0f) + ox * (1.0f / 128.0f)) * 128.0f - 0.5f;
        const float py = (gi * (1.0f / 127.0f) + oy * (1.0f / 128.0f)) * 128.0f - 0.5f;
        const float x0f = floorf(px), y0f = floorf(py);
        const int   x0 = (int)x0f, y0 = (int)y0f;
        const float fx = px - x0f, fy = py - y0f;
        const int x0c = min(max(x0, 0), 127), x1c = min(max(x0 + 1, 0), 127);
        const int y0c = min(max(y0, 0), 127), y1c = min(max(y0 + 1, 0), 127);
        const float vx0 = ((unsigned)x0 <= 127u) ? 1.f : 0.f;
        const float vx1 = ((unsigned)(x0 + 1) <= 127u) ? 1.f : 0.f;
        const float vy0 = ((unsigned)y0 <= 127u) ? 1.f : 0.f;
        const float vy1 = ((unsigned)(y0 + 1) <= 127u) ? 1.f : 0.f;

        s_off[g][cmb][0] = (y0c * 128 + x0c) * 512;
        s_off[g][cmb][1] = (y0c * 128 + x1c) * 512;
        s_off[g][cmb][2] = (y1c * 128 + x0c) * 512;
        s_off[g][cmb][3] = (y1c * 128 + x1c) * 512;
        s_c[g][cmb][0] = aw * (1.f - fx) * (1.f - fy) * vx0 * vy0;
        s_c[g][cmb][1] = aw * fx * (1.f - fy) * vx1 * vy0;
        s_c[g][cmb][2] = aw * (1.f - fx) * fy * vx0 * vy1;
        s_c[g][cmb][3] = aw * fx * fy * vx1 * vy1;
    }
    __syncthreads();

    const int half = t >> 7;
    const int h    = (t >> 4) & 7;
    const int dd   = t & 15;
    const char* vb = (const char*)vcomp + ((size_t)bq * NQ_ * 256 + h * 32 + dd * 2) * 2;

    #pragma unroll
    for (int it = 0; it < 4; ++it) {
        const int g = it * 2 + half;
        float a0 = 0.f, a1 = 0.f;
        #pragma unroll
        for (int p = 0; p < 4; ++p) {
            const int cmb = h * 4 + p;
            #pragma unroll
            for (int k = 0; k < 4; ++k) {
                const unsigned u = *(const unsigned*)(vb + s_off[g][cmb][k]);
                const float c = s_c[g][cmb][k];
                a0 += c * __uint_as_float(u << 16);
                a1 += c * __uint_as_float(u & 0xffff0000u);
            }
        }
        const int r = r0 + g;
        const unsigned o = (unsigned)(unsigned short)f2bf(a0)
                         | ((unsigned)(unsigned short)f2bf(a1) << 16);
        *(unsigned*)&msda[(size_t)r * 256 + h * 32 + dd * 2] = o;
    }
}

// ---------------------------------------------------------------------------
extern "C" void kernel_launch(void* const* d_in, const int* in_sizes, int n_in,
                              void* d_out, int out_size, void* d_ws, size_t ws_size,
                              hipStream_t stream) {
    const float* q      = (const float*)d_in[0];
    const float* b_out  = (const float*)d_in[8];
    const float* b1     = (const float*)d_in[10];
    const float* b2     = (const float*)d_in[12];
    const float* gamma  = (const float*)d_in[13];
    const float* beta   = (const float*)d_in[14];

    float* out = (float*)d_out;

    char* w = (char*)d_ws;
    float* pm    = (float*)w; w += (size_t)RTOT_ * 128 * 4;      // 16.8 MB
    short* vcomp = (short*)w; w += (size_t)RTOT_ * 256 * 2;      // 16.8 MB
    short* qbf   = (short*)w; w += (size_t)RTOT_ * EMBED_ * 2;   // 16.8 MB
    short* msda  = (short*)w; w += (size_t)RTOT_ * EMBED_ * 2;   // 16.8 MB
    short* xbf   = (short*)w; w += (size_t)RTOT_ * EMBED_ * 2;   // 16.8 MB
    short* hid   = (short*)w; w += (size_t)RTOT_ * FFN_ * 2;     // 33.6 MB
    short* WcatT = (short*)w; w += WCAT_ELEMS * 2;
    short* WoutT = (short*)w; w += WOUT_ELEMS * 2;
    short* W1T   = (short*)w; w += W1_ELEMS * 2;
    short* W2T   = (short*)w; w += W2_ELEMS * 2;
    float* bcat  = (float*)w; w += NCATP_ * 4;

    // weight prep only
    prep_weights<<<PREP_BLOCKS, 256, 0, stream>>>(
        (const float*)d_in[5], (const float*)d_in[1], (const float*)d_in[3],
        (const float*)d_in[6], (const float*)d_in[2], (const float*)d_in[4],
        (const float*)d_in[7], (const float*)d_in[9], (const float*)d_in[11],
        WcatT, WoutT, W1T, W2T, bcat);

    // fused q-cvt + proj: qbf, vcomp, pm   (32768 x 384 x 256, A-resident)
    gemm1_fused<<<RTOT_ / 128, 512, 0, stream>>>(
        q, WcatT, bcat, qbf, vcomp, pm);

    // MSDA sampling -> msda (bf16)
    msda_sample<<<RTOT_ / 8, 256, 0, stream>>>(pm, vcomp, msda);

    // fused: xbf = bf16(msda@W_out + b_out + 2q); hid = relu(x@W1 + b1)
    gemm_x_ffn1<<<RTOT_ / 128, 512, 0, stream>>>(
        msda, WoutT, b_out, qbf, W1T, b1, xbf, hid);

    // out = x + LN(hid @ W2 + b2)*gamma + beta
    gemm_ln<<<RTOT_ / 64, 256, 0, stream>>>(
        hid, W2T, b2, xbf, gamma, beta, out, RTOT_, FFN_);
}